// Round 1
// baseline (152.868 us; speedup 1.0000x reference)
//
#include <hip/hip_runtime.h>
#include <hip/hip_bf16.h>
#include <stdint.h>

// Problem constants (B=16, S=1024, E=8 qubits -> 2^8 = 256 amplitudes).
#define NB 16
#define S_LEN 1024
#define E_Q 8

typedef float v4f __attribute__((ext_vector_type(4)));
typedef short v8s __attribute__((ext_vector_type(8)));
typedef int   v4i __attribute__((ext_vector_type(4)));

// ---------------------------------------------------------------------------
// Kernel 1: per-token cos/sin feature tables.
// For token x, basis state z with signs s_i = (-1)^{z_i}:
//   L = sum_i x_i s_i,  phi = -0.5 L - 0.25 (L^2 - ||x||^2)
// Table row (512 bf16): [cos phi(z) for z=0..255 | sin phi(z) for z=0..255]
// Each block handles 16 tokens; thread (t&15) owns 16 z values of token t>>4.
// ---------------------------------------------------------------------------
__global__ __launch_bounds__(256) void build_tables(
    const float* __restrict__ Q, const float* __restrict__ K,
    uint16_t* __restrict__ Aq, uint16_t* __restrict__ Kt)
{
    const int which = blockIdx.y;
    const float* X = which ? K : Q;
    uint16_t*   T  = which ? Kt : Aq;

    const int tok = blockIdx.x * 16 + (threadIdx.x >> 4);
    const int zb  = (threadIdx.x & 15) * 16;

    const float* x = X + tok * E_Q;
    float xv[E_Q]; float sq = 0.f;
#pragma unroll
    for (int i = 0; i < E_Q; ++i) { xv[i] = x[i]; sq += xv[i] * xv[i]; }

    uint16_t* dst = T + (size_t)tok * 512;
#pragma unroll
    for (int zz = 0; zz < 16; ++zz) {
        const int z = zb + zz;
        float L = 0.f;
#pragma unroll
        for (int i = 0; i < E_Q; ++i) L += ((z >> i) & 1) ? -xv[i] : xv[i];
        const float phi = fmaf(-0.25f, L * L, fmaf(-0.5f, L, 0.25f * sq));
        float s, c;
        sincosf(phi, &s, &c);
        __hip_bfloat16 cb = __float2bfloat16(c);
        __hip_bfloat16 sb = __float2bfloat16(s);
        dst[z]       = *(const uint16_t*)&cb;
        dst[z + 256] = *(const uint16_t*)&sb;
    }
}

// ---------------------------------------------------------------------------
// Kernel 2: QK fidelity GEMM + nonlinearity -> attn (bf16, [B][S][S]).
//   Re = cq.ck + sq.sk          (A = Q-table, B = K-table, both [tok][512])
//   Im = cq.sk + sq.(-ck)       (-ck derived in-register via bf16 sign flip)
//   attn = 2^-15 (Re^2 + Im^2) - 1
// Block tile 128(i) x 128(j), K-chunks of 32 over c=0..255 (cos/sin halves
// staged as separate 128x32 tiles). 4 waves, each owns a 64x64 quadrant
// (4x4 frags of 16x16x32 MFMA, Re+Im => 32 f32x4 accumulators).
// global_load_lds width=16; XOR swizzle (chunk q ^= row&3) keeps b128 frag
// reads at 2-way bank aliasing (free) instead of 8-way.
// ---------------------------------------------------------------------------
__global__ __launch_bounds__(256, 2) void qk_attn(
    const uint16_t* __restrict__ Aq, const uint16_t* __restrict__ Kt,
    uint16_t* __restrict__ attn)
{
    __shared__ uint16_t lAc[128 * 32];   // cos half of A chunk
    __shared__ uint16_t lAs[128 * 32];   // sin half of A chunk
    __shared__ uint16_t lKc[128 * 32];   // cos half of K chunk
    __shared__ uint16_t lKs[128 * 32];   // sin half of K chunk

    const int jblk = blockIdx.x, iblk = blockIdx.y, b = blockIdx.z;
    const int tid  = threadIdx.x;
    const int lane = tid & 63, wv = tid >> 6;
    const int wm = wv >> 1, wn = wv & 1;          // wave quadrant
    const int r15 = lane & 15, qq = lane >> 4;

    // Fragment read offset in uint16 units (row-major [row][32], 64 B rows),
    // with the XOR de-swizzle: logical 16B-chunk q lives at slot q ^ (row&3).
    const int fr_off = r15 * 32 + ((qq ^ (r15 & 3)) * 8);

    // Staging: 512 16B-chunks per tile, 2 per thread. Chunk f = p*256 + tid
    // fills LDS bytes f*16; its global source is (row f>>2, column (f&3)^(row&3)).
    int goff[2], loff[2];
#pragma unroll
    for (int p = 0; p < 2; ++p) {
        const int f = p * 256 + tid;
        const int r = f >> 2, qs = f & 3;
        goff[p] = r * 1024 + ((qs ^ (r & 3)) * 16);   // global byte offset
        loff[p] = p * 4096 + wv * 1024;               // wave-uniform LDS base
    }

    const char* gA = (const char*)Aq + (size_t)(b * S_LEN + iblk * 128) * 1024;
    const char* gK = (const char*)Kt + (size_t)(b * S_LEN + jblk * 128) * 1024;

    v4f accRe[4][4], accIm[4][4];
#pragma unroll
    for (int mi = 0; mi < 4; ++mi)
#pragma unroll
        for (int ni = 0; ni < 4; ++ni) {
            accRe[mi][ni] = (v4f)0.f;
            accIm[mi][ni] = (v4f)0.f;
        }

    for (int c = 0; c < 8; ++c) {
        __syncthreads();   // previous compute done before overwriting LDS
        const int cb = c * 64;   // 32 elems * 2 B per chunk column step
#pragma unroll
        for (int p = 0; p < 2; ++p) {
            __builtin_amdgcn_global_load_lds(
                (const __attribute__((address_space(1))) void*)(gA + cb + goff[p]),
                (__attribute__((address_space(3))) void*)((char*)lAc + loff[p]), 16, 0, 0);
            __builtin_amdgcn_global_load_lds(
                (const __attribute__((address_space(1))) void*)(gA + 512 + cb + goff[p]),
                (__attribute__((address_space(3))) void*)((char*)lAs + loff[p]), 16, 0, 0);
            __builtin_amdgcn_global_load_lds(
                (const __attribute__((address_space(1))) void*)(gK + cb + goff[p]),
                (__attribute__((address_space(3))) void*)((char*)lKc + loff[p]), 16, 0, 0);
            __builtin_amdgcn_global_load_lds(
                (const __attribute__((address_space(1))) void*)(gK + 512 + cb + goff[p]),
                (__attribute__((address_space(3))) void*)((char*)lKs + loff[p]), 16, 0, 0);
        }
        __syncthreads();   // compiler drains vmcnt before s_barrier

        v8s aq[4], as[4];
#pragma unroll
        for (int mi = 0; mi < 4; ++mi) {
            aq[mi] = *(const v8s*)&lAc[(wm * 64 + mi * 16) * 32 + fr_off];
            as[mi] = *(const v8s*)&lAs[(wm * 64 + mi * 16) * 32 + fr_off];
        }
#pragma unroll
        for (int ni = 0; ni < 4; ++ni) {
            const v8s kc = *(const v8s*)&lKc[(wn * 64 + ni * 16) * 32 + fr_off];
            const v8s ks = *(const v8s*)&lKs[(wn * 64 + ni * 16) * 32 + fr_off];
            v4i kci = __builtin_bit_cast(v4i, kc);
            kci ^= (int)0x80008000;                    // bf16 sign flip: -ck
            const v8s nkc = __builtin_bit_cast(v8s, kci);
#pragma unroll
            for (int mi = 0; mi < 4; ++mi) {
                accRe[mi][ni] = __builtin_amdgcn_mfma_f32_16x16x32_bf16(aq[mi], kc,  accRe[mi][ni], 0, 0, 0);
                accRe[mi][ni] = __builtin_amdgcn_mfma_f32_16x16x32_bf16(as[mi], ks,  accRe[mi][ni], 0, 0, 0);
                accIm[mi][ni] = __builtin_amdgcn_mfma_f32_16x16x32_bf16(aq[mi], ks,  accIm[mi][ni], 0, 0, 0);
                accIm[mi][ni] = __builtin_amdgcn_mfma_f32_16x16x32_bf16(as[mi], nkc, accIm[mi][ni], 0, 0, 0);
            }
        }
    }

    // Epilogue: attn = 2^-15 (Re^2 + Im^2) - 1, bf16.
    // C-layout (verified m89): col = lane&15, row = (lane>>4)*4 + reg.
    const float sc = 3.0517578125e-05f;   // 2^-15
    uint16_t* ab_base = attn + ((size_t)b << 20);
#pragma unroll
    for (int mi = 0; mi < 4; ++mi) {
#pragma unroll
        for (int ni = 0; ni < 4; ++ni) {
#pragma unroll
            for (int rg = 0; rg < 4; ++rg) {
                const float re = accRe[mi][ni][rg];
                const float im = accIm[mi][ni][rg];
                const float a  = fmaf(re * re + im * im, sc, -1.0f);
                const int i = iblk * 128 + wm * 64 + mi * 16 + qq * 4 + rg;
                const int j = jblk * 128 + wn * 64 + ni * 16 + r15;
                __hip_bfloat16 ab = __float2bfloat16(a);
                ab_base[((size_t)i << 10) + j] = *(const uint16_t*)&ab;
            }
        }
    }
}

// ---------------------------------------------------------------------------
// Kernel 3: out = attn @ V.  Block = 64 rows of one batch; V (32 KB fp32) in
// LDS; each lane owns one row, the 4 waves split j into quarters, LDS reduce.
// ---------------------------------------------------------------------------
__global__ __launch_bounds__(256) void pv_out(
    const uint16_t* __restrict__ attn, const float* __restrict__ V,
    float* __restrict__ out)
{
    __shared__ float Vl[S_LEN * E_Q];        // 32 KB
    __shared__ float part[4][64][E_Q];       // 8 KB

    const int b = blockIdx.y, rb = blockIdx.x;
    const int tid = threadIdx.x;

    // Stage V[b] (8192 floats) coalesced.
    const float4* vsrc = (const float4*)(V + (size_t)b * S_LEN * E_Q);
    float4* vdst = (float4*)Vl;
    for (int idx = tid; idx < S_LEN * E_Q / 4; idx += 256) vdst[idx] = vsrc[idx];
    __syncthreads();

    const int lane = tid & 63, wv = tid >> 6;
    const int i = rb * 64 + lane;
    const uint16_t* arow = attn + ((size_t)b << 20) + ((size_t)i << 10) + wv * 256;

    float acc[E_Q];
#pragma unroll
    for (int e = 0; e < E_Q; ++e) acc[e] = 0.f;

    for (int jj = 0; jj < 256; jj += 8) {
        const uint4 a8 = *(const uint4*)(arow + jj);
        const uint32_t w[4] = {a8.x, a8.y, a8.z, a8.w};
#pragma unroll
        for (int k = 0; k < 8; ++k) {
            const uint32_t raw = (w[k >> 1] >> (16 * (k & 1))) & 0xffffu;
            const float av = __uint_as_float(raw << 16);
            const float* vp = &Vl[(wv * 256 + jj + k) * E_Q];   // wave-uniform addr -> broadcast
#pragma unroll
            for (int e = 0; e < E_Q; ++e) acc[e] = fmaf(av, vp[e], acc[e]);
        }
    }

#pragma unroll
    for (int e = 0; e < E_Q; ++e) part[wv][lane][e] = acc[e];
    __syncthreads();

    for (int o = tid; o < 64 * E_Q; o += 256) {
        const int li = o >> 3, e = o & 7;
        const float s = part[0][li][e] + part[1][li][e] + part[2][li][e] + part[3][li][e];
        out[((size_t)b * S_LEN + rb * 64 + li) * E_Q + e] = s;
    }
}

// ---------------------------------------------------------------------------
// Workspace layout (64 MB total):
//   [0,  16 MB)  Aq  : Q tables, [16*1024][512] bf16
//   [16, 32 MB)  Kt  : K tables, [16*1024][512] bf16
//   [32, 64 MB)  attn: [16][1024][1024] bf16
// ---------------------------------------------------------------------------
extern "C" void kernel_launch(void* const* d_in, const int* in_sizes, int n_in,
                              void* d_out, int out_size, void* d_ws, size_t ws_size,
                              hipStream_t stream) {
    const float* Q = (const float*)d_in[0];
    const float* K = (const float*)d_in[1];
    const float* V = (const float*)d_in[2];
    float* out = (float*)d_out;

    uint16_t* Aq   = (uint16_t*)d_ws;
    uint16_t* Kt   = (uint16_t*)((char*)d_ws + (size_t)16 * 1024 * 1024);
    uint16_t* attn = (uint16_t*)((char*)d_ws + (size_t)32 * 1024 * 1024);

    build_tables<<<dim3(NB * S_LEN / 16, 2), 256, 0, stream>>>(Q, K, Aq, Kt);
    qk_attn<<<dim3(S_LEN / 128, S_LEN / 128, NB), 256, 0, stream>>>(Aq, Kt, attn);
    pv_out<<<dim3(S_LEN / 64, NB), 256, 0, stream>>>(attn, V, out);
}

// Round 2
// 110.917 us; speedup vs baseline: 1.3782x; 1.3782x over previous
//
#include <hip/hip_runtime.h>
#include <hip/hip_bf16.h>
#include <stdint.h>

// Problem constants (B=16, S=1024, E=8 qubits -> 2^8 = 256 amplitudes).
#define NB 16
#define S_LEN 1024
#define E_Q 8

typedef float v4f __attribute__((ext_vector_type(4)));
typedef short v8s __attribute__((ext_vector_type(8)));
typedef int   v4i __attribute__((ext_vector_type(4)));

// ---------------------------------------------------------------------------
// Kernel 1: per-token cos/sin feature tables.
//   L = sum_i x_i s_i,  phi = -0.5 L - 0.25 (L^2 - ||x||^2),  s_i=(-1)^{z_i}
// Row (512 bf16): [cos phi(z), z=0..255 | sin phi(z), z=0..255]
// __sincosf (fast path): phase err ~1e-5 << bf16 quantization 4e-3.
// ---------------------------------------------------------------------------
__global__ __launch_bounds__(256) void build_tables(
    const float* __restrict__ Q, const float* __restrict__ K,
    uint16_t* __restrict__ Aq, uint16_t* __restrict__ Kt)
{
    const float* X = blockIdx.y ? K : Q;
    uint16_t*   T  = blockIdx.y ? Kt : Aq;

    const int tok = blockIdx.x * 16 + (threadIdx.x >> 4);
    const int zb  = (threadIdx.x & 15) * 16;

    const float* x = X + tok * E_Q;
    float xv[E_Q]; float sq = 0.f;
#pragma unroll
    for (int i = 0; i < E_Q; ++i) { xv[i] = x[i]; sq += xv[i] * xv[i]; }

    __align__(16) uint16_t cb[16];
    __align__(16) uint16_t sb[16];
#pragma unroll
    for (int zz = 0; zz < 16; ++zz) {
        const int z = zb + zz;
        float L = 0.f;
#pragma unroll
        for (int i = 0; i < E_Q; ++i) L += ((z >> i) & 1) ? -xv[i] : xv[i];
        const float phi = fmaf(-0.25f, L * L, fmaf(-0.5f, L, 0.25f * sq));
        float s, c;
        __sincosf(phi, &s, &c);
        __hip_bfloat16 cbf = __float2bfloat16(c);
        __hip_bfloat16 sbf = __float2bfloat16(s);
        cb[zz] = *(const uint16_t*)&cbf;
        sb[zz] = *(const uint16_t*)&sbf;
    }
    uint16_t* dst = T + (size_t)tok * 512;
    *(uint4*)(dst + zb)           = ((const uint4*)cb)[0];
    *(uint4*)(dst + zb + 8)       = ((const uint4*)cb)[1];
    *(uint4*)(dst + 256 + zb)     = ((const uint4*)sb)[0];
    *(uint4*)(dst + 256 + zb + 8) = ((const uint4*)sb)[1];
}

// ---------------------------------------------------------------------------
// Kernel 2: fused QK fidelity GEMM + nonlinearity + PV partial.
//   Re = cq.ck + sq.sk ; Im = cq.sk + sq.(-ck)   (bf16 sign-flip in register)
//   attn = 2^-15 (Re^2+Im^2) - 1
//   part[b][jblk][i][e] = sum_{j in jblk tile} attn[i][j] * V[j][e]
// Block tile 128x128, BK=64 (two paired 32-chunks c and c+8 of the cos/sin
// halves), 4 K-iterations of 128 MFMA each (vs 8x64 before: half the
// barrier-drain stalls). LDS phase 1: 4 tiles [128][64] bf16 = 64 KB with
// XOR chunk swizzle (slot = q ^ (row&7)) -> uniform bank spread on b128
// frag reads. Phase 2 aliases the same LDS: attn tile bf16 [128][128]
// (32 KB) + V tile split A/B (4 KB).
// ---------------------------------------------------------------------------
__global__ __launch_bounds__(256, 2) void qk_pv(
    const uint16_t* __restrict__ Aq, const uint16_t* __restrict__ Kt,
    const float* __restrict__ V, float* __restrict__ part)
{
    __shared__ __align__(16) char smem[65536];
    uint16_t* lAc = (uint16_t*)smem;                // [128][64]
    uint16_t* lAs = (uint16_t*)(smem + 16384);
    uint16_t* lKc = (uint16_t*)(smem + 32768);
    uint16_t* lKs = (uint16_t*)(smem + 49152);
    // phase-2 aliases (valid after the post-K-loop barrier)
    uint16_t* lattn = (uint16_t*)smem;              // [128][128] bf16
    float*    VtA   = (float*)(smem + 32768);       // [128] float4 (e0..3)
    float*    VtB   = (float*)(smem + 34816);       // [128] float4 (e4..7)

    const int jblk = blockIdx.x, iblk = blockIdx.y, b = blockIdx.z;
    const int tid  = threadIdx.x;
    const int lane = tid & 63, wv = tid >> 6;
    const int wm = wv >> 1, wn = wv & 1;            // wave quadrant
    const int r15 = lane & 15, qq = lane >> 4;

    // Staging: each tile = 1024 16B-chunks; thread stages chunk f = p*256+tid.
    // Chunk f -> LDS byte f*16 (wave-uniform base + lane*16); source row
    // r = f>>3, swizzled logical chunk q = (f&7) ^ (r&7).
    int goff[4];
#pragma unroll
    for (int p = 0; p < 4; ++p) {
        const int f = p * 256 + tid;
        const int r = f >> 3, q = (f & 7) ^ (r & 7);
        goff[p] = r * 1024 + q * 16;                 // global byte offset
    }
    const int lbase = wv * 1024;                     // wave-uniform LDS base

    const char* gA = (const char*)Aq + (size_t)(b * S_LEN + iblk * 128) * 1024;
    const char* gK = (const char*)Kt + (size_t)(b * S_LEN + jblk * 128) * 1024;

    v4f accRe[4][4], accIm[4][4];
#pragma unroll
    for (int mi = 0; mi < 4; ++mi)
#pragma unroll
        for (int ni = 0; ni < 4; ++ni) {
            accRe[mi][ni] = (v4f)0.f;
            accIm[mi][ni] = (v4f)0.f;
        }

    for (int c = 0; c < 4; ++c) {
        __syncthreads();                             // LDS safe to overwrite
        const int cbyte = c * 128;                   // 64 elems * 2 B
#pragma unroll
        for (int p = 0; p < 4; ++p) {
            const int lo = p * 4096 + lbase;
            const char* sA = gA + cbyte + goff[p];
            const char* sK = gK + cbyte + goff[p];
            __builtin_amdgcn_global_load_lds(
                (const __attribute__((address_space(1))) void*)sA,
                (__attribute__((address_space(3))) void*)((char*)lAc + lo), 16, 0, 0);
            __builtin_amdgcn_global_load_lds(
                (const __attribute__((address_space(1))) void*)(sA + 512),
                (__attribute__((address_space(3))) void*)((char*)lAs + lo), 16, 0, 0);
            __builtin_amdgcn_global_load_lds(
                (const __attribute__((address_space(1))) void*)sK,
                (__attribute__((address_space(3))) void*)((char*)lKc + lo), 16, 0, 0);
            __builtin_amdgcn_global_load_lds(
                (const __attribute__((address_space(1))) void*)(sK + 512),
                (__attribute__((address_space(3))) void*)((char*)lKs + lo), 16, 0, 0);
        }
        __syncthreads();                             // drain staging

#pragma unroll
        for (int ks2 = 0; ks2 < 2; ++ks2) {
            const int sl = ((ks2 * 4 + qq) ^ (r15 & 7)) * 8;
            v8s aqf[4], asf[4];
#pragma unroll
            for (int mi = 0; mi < 4; ++mi) {
                const int off = (wm * 64 + mi * 16 + r15) * 64 + sl;
                aqf[mi] = *(const v8s*)&lAc[off];
                asf[mi] = *(const v8s*)&lAs[off];
            }
#pragma unroll
            for (int ni = 0; ni < 4; ++ni) {
                const int koff = (wn * 64 + ni * 16 + r15) * 64 + sl;
                const v8s kc = *(const v8s*)&lKc[koff];
                const v8s ks = *(const v8s*)&lKs[koff];
                v4i kci = __builtin_bit_cast(v4i, kc);
                kci ^= (int)0x80008000;              // bf16 sign flip: -ck
                const v8s nkc = __builtin_bit_cast(v8s, kci);
#pragma unroll
                for (int mi = 0; mi < 4; ++mi) {
                    accRe[mi][ni] = __builtin_amdgcn_mfma_f32_16x16x32_bf16(aqf[mi], kc,  accRe[mi][ni], 0, 0, 0);
                    accRe[mi][ni] = __builtin_amdgcn_mfma_f32_16x16x32_bf16(asf[mi], ks,  accRe[mi][ni], 0, 0, 0);
                    accIm[mi][ni] = __builtin_amdgcn_mfma_f32_16x16x32_bf16(aqf[mi], ks,  accIm[mi][ni], 0, 0, 0);
                    accIm[mi][ni] = __builtin_amdgcn_mfma_f32_16x16x32_bf16(asf[mi], nkc, accIm[mi][ni], 0, 0, 0);
                }
            }
        }
    }

    // ---- Epilogue phase: attn tile -> LDS (bf16), V tile -> LDS ----
    __syncthreads();                                 // all frag reads done
    // V[b][jblk*128 + (tid>>1)][ (tid&1)*4 .. +4 ]  (issue load early)
    const float4 vreg = ((const float4*)(V + ((size_t)b * S_LEN + jblk * 128) * E_Q))[tid];

    const float sc = 3.0517578125e-05f;              // 2^-15
    // C-layout (m89): col = lane&15, row = (lane>>4)*4 + reg
#pragma unroll
    for (int mi = 0; mi < 4; ++mi) {
#pragma unroll
        for (int ni = 0; ni < 4; ++ni) {
#pragma unroll
            for (int rg = 0; rg < 4; ++rg) {
                const float re = accRe[mi][ni][rg];
                const float im = accIm[mi][ni][rg];
                const float a  = fmaf(re * re + im * im, sc, -1.0f);
                const int row = wm * 64 + mi * 16 + qq * 4 + rg;
                const int col = wn * 64 + ni * 16 + r15;
                __hip_bfloat16 ab = __float2bfloat16(a);
                lattn[row * 128 + col] = *(const uint16_t*)&ab;
            }
        }
    }
    ((float4*)((tid & 1) ? VtB : VtA))[tid >> 1] = vreg;
    __syncthreads();

    // ---- Phase 2: part[128][8] = attnTile[128x128] @ Vt[128][8] ----
    const int r  = tid >> 1;                         // output row in tile
    const int hf = tid & 1;                          // e-half
    const float* vt = hf ? VtB : VtA;
    float ax = 0.f, ay = 0.f, az = 0.f, aw = 0.f;
#pragma unroll 4
    for (int j = 0; j < 128; ++j) {
        const int jj = (j + r) & 127;                // bank rotation
        const uint32_t raw = lattn[r * 128 + jj];
        const float a = __uint_as_float(raw << 16);
        const float4 vv = *(const float4*)&vt[jj * 4];
        ax = fmaf(a, vv.x, ax);
        ay = fmaf(a, vv.y, ay);
        az = fmaf(a, vv.z, az);
        aw = fmaf(a, vv.w, aw);
    }
    float* pdst = part + ((((size_t)b * 8 + jblk) * 1024) + iblk * 128 + r) * 8 + hf * 4;
    float4 res; res.x = ax; res.y = ay; res.z = az; res.w = aw;
    *(float4*)pdst = res;
}

// ---------------------------------------------------------------------------
// Kernel 3: out[b][i][e] = sum_{jb=0..8} part[b][jb][i][e].   4 MB -> 0.5 MB.
// ---------------------------------------------------------------------------
__global__ __launch_bounds__(256) void reduce_out(
    const float* __restrict__ part, float* __restrict__ out)
{
    const int o = blockIdx.x * 256 + threadIdx.x;    // float4 index, 32768 total
    const int b = o >> 11, rem = o & 2047;           // 2048 float4 per batch
    const float4* p = (const float4*)part + (size_t)b * 8 * 2048 + rem;
    float4 s = p[0];
#pragma unroll
    for (int jb = 1; jb < 8; ++jb) {
        const float4 t = p[(size_t)jb * 2048];
        s.x += t.x; s.y += t.y; s.z += t.z; s.w += t.w;
    }
    ((float4*)out)[o] = s;
}

// ---------------------------------------------------------------------------
// Workspace layout (36 MB used):
//   [0,  16 MB)  Aq   : Q tables, [16*1024][512] bf16
//   [16, 32 MB)  Kt   : K tables, [16*1024][512] bf16
//   [32, 36 MB)  part : [16][8][1024][8] f32 PV partials
// ---------------------------------------------------------------------------
extern "C" void kernel_launch(void* const* d_in, const int* in_sizes, int n_in,
                              void* d_out, int out_size, void* d_ws, size_t ws_size,
                              hipStream_t stream) {
    const float* Q = (const float*)d_in[0];
    const float* K = (const float*)d_in[1];
    const float* V = (const float*)d_in[2];
    float* out = (float*)d_out;

    uint16_t* Aq   = (uint16_t*)d_ws;
    uint16_t* Kt   = (uint16_t*)((char*)d_ws + (size_t)16 * 1024 * 1024);
    float*    part = (float*)((char*)d_ws + (size_t)32 * 1024 * 1024);

    build_tables<<<dim3(NB * S_LEN / 16, 2), 256, 0, stream>>>(Q, K, Aq, Kt);
    qk_pv<<<dim3(S_LEN / 128, S_LEN / 128, NB), 256, 0, stream>>>(Aq, Kt, V, part);
    reduce_out<<<dim3(NB * S_LEN * E_Q / 4 / 256), 256, 0, stream>>>(part, out);
}

// Round 3
// 102.396 us; speedup vs baseline: 1.4929x; 1.0832x over previous
//
#include <hip/hip_runtime.h>
#include <hip/hip_bf16.h>
#include <stdint.h>

// Problem constants (B=16, S=1024, E=8 qubits -> 2^8 = 256 amplitudes).
#define NB 16
#define S_LEN 1024
#define E_Q 8

typedef float v4f __attribute__((ext_vector_type(4)));
typedef short v8s __attribute__((ext_vector_type(8)));
typedef int   v4i __attribute__((ext_vector_type(4)));

// ---------------------------------------------------------------------------
// Kernel 1: per-token cos/sin feature tables.
//   L = sum_i x_i s_i,  phi = -0.5 L - 0.25 (L^2 - ||x||^2),  s_i=(-1)^{z_i}
// Row (512 bf16): [cos phi(z), z=0..255 | sin phi(z), z=0..255]
// Thread owns 16 z values (upper nibble fixed = tid&15); walks the lower
// nibble in GRAY-CODE order so each L update is a single fma (vs 8
// select-adds). All indices constant-fold under full unroll.
// ---------------------------------------------------------------------------
__global__ __launch_bounds__(256) void build_tables(
    const float* __restrict__ Q, const float* __restrict__ K,
    uint16_t* __restrict__ Aq, uint16_t* __restrict__ Kt)
{
    const float* X = blockIdx.y ? K : Q;
    uint16_t*   T  = blockIdx.y ? Kt : Aq;

    const int tok = blockIdx.x * 16 + (threadIdx.x >> 4);
    const int hi  = threadIdx.x & 15;     // z bits 4..7
    const int zb  = hi * 16;

    const float* x = X + tok * E_Q;
    float xv[E_Q]; float sq = 0.f;
#pragma unroll
    for (int i = 0; i < E_Q; ++i) { xv[i] = x[i]; sq += xv[i] * xv[i]; }
    const float qsq = 0.25f * sq;

    // L at z = zb: low 4 bits are 0 (sign +), high bits from `hi`.
    float L = xv[0] + xv[1] + xv[2] + xv[3];
#pragma unroll
    for (int i = 4; i < 8; ++i) L += ((hi >> (i - 4)) & 1) ? -xv[i] : xv[i];

    __align__(16) uint16_t cb[16];
    __align__(16) uint16_t sb[16];

    {   // n = 0, gray = 0
        const float phi = fmaf(-0.25f, L * L, fmaf(-0.5f, L, qsq));
        float s, c; __sincosf(phi, &s, &c);
        __hip_bfloat16 cbf = __float2bfloat16(c), sbf = __float2bfloat16(s);
        cb[0] = *(const uint16_t*)&cbf; sb[0] = *(const uint16_t*)&sbf;
    }
#pragma unroll
    for (int n = 1; n < 16; ++n) {
        const int g  = n ^ (n >> 1);
        const int gp = (n - 1) ^ ((n - 1) >> 1);
        const int t  = __builtin_ctz(g ^ gp);        // constant-folds
        const float twox = 2.0f * xv[t];
        L = ((g >> t) & 1) ? (L - twox) : (L + twox);
        const float phi = fmaf(-0.25f, L * L, fmaf(-0.5f, L, qsq));
        float s, c; __sincosf(phi, &s, &c);
        __hip_bfloat16 cbf = __float2bfloat16(c), sbf = __float2bfloat16(s);
        cb[g] = *(const uint16_t*)&cbf; sb[g] = *(const uint16_t*)&sbf;
    }

    uint16_t* dst = T + (size_t)tok * 512;
    *(uint4*)(dst + zb)           = ((const uint4*)cb)[0];
    *(uint4*)(dst + zb + 8)       = ((const uint4*)cb)[1];
    *(uint4*)(dst + 256 + zb)     = ((const uint4*)sb)[0];
    *(uint4*)(dst + 256 + zb + 8) = ((const uint4*)sb)[1];
}

// ---------------------------------------------------------------------------
// Kernel 2: fused QK fidelity GEMM + nonlinearity + MFMA PV + atomic out.
// Phase 1 (unchanged from R2): 128x128 tile, BK=64, 4 K-iters of 128 MFMA,
//   XOR-swizzled [128][64] staging tiles (64 KB), global_load_lds width=16.
// Epilogue: attn = 2^-15(Re^2+Im^2)-1 -> bf16 LDS [128][136] (pad 136 ->
//   balanced 8-lane/4-bank-group b128 A-frag reads); V^T bf16 [16][136].
// Phase 2: out-tile = attnTile @ V via 8 MFMAs/wave (N=16; cols 8..15 are
//   garbage-but-finite, never stored), then f32 atomicAdd into d_out
//   (zeroed by a memset node in the graph).
// ---------------------------------------------------------------------------
__global__ __launch_bounds__(256, 2) void qk_pv(
    const uint16_t* __restrict__ Aq, const uint16_t* __restrict__ Kt,
    const float* __restrict__ V, float* __restrict__ out)
{
    __shared__ __align__(16) char smem[65536];
    uint16_t* lAc = (uint16_t*)smem;                // [128][64]
    uint16_t* lAs = (uint16_t*)(smem + 16384);
    uint16_t* lKc = (uint16_t*)(smem + 32768);
    uint16_t* lKs = (uint16_t*)(smem + 49152);
    // phase-2 aliases (valid after the post-K-loop barrier)
    uint16_t* lattn = (uint16_t*)smem;              // [128][136] bf16
    uint16_t* lVt   = (uint16_t*)(smem + 34816);    // [16][136]  bf16 (V^T)

    const int jblk = blockIdx.x, iblk = blockIdx.y, b = blockIdx.z;
    const int tid  = threadIdx.x;
    const int lane = tid & 63, wv = tid >> 6;
    const int wm = wv >> 1, wn = wv & 1;            // wave quadrant
    const int r15 = lane & 15, qq = lane >> 4;

    // Staging: each tile = 1024 16B-chunks; thread stages chunk f = p*256+tid.
    // LDS byte f*16 (wave-uniform base + lane*16); source row r = f>>3,
    // swizzled logical chunk q = (f&7) ^ (r&7).
    int goff[4];
#pragma unroll
    for (int p = 0; p < 4; ++p) {
        const int f = p * 256 + tid;
        const int r = f >> 3, q = (f & 7) ^ (r & 7);
        goff[p] = r * 1024 + q * 16;                 // global byte offset
    }
    const int lbase = wv * 1024;                     // wave-uniform LDS base

    const char* gA = (const char*)Aq + (size_t)(b * S_LEN + iblk * 128) * 1024;
    const char* gK = (const char*)Kt + (size_t)(b * S_LEN + jblk * 128) * 1024;

    // V tile load issued early: V[b][jblk*128 + (tid>>1)][(tid&1)*4 .. +4]
    const float4 vreg = ((const float4*)(V + ((size_t)b * S_LEN + jblk * 128) * E_Q))[tid];

    v4f accRe[4][4], accIm[4][4];
#pragma unroll
    for (int mi = 0; mi < 4; ++mi)
#pragma unroll
        for (int ni = 0; ni < 4; ++ni) {
            accRe[mi][ni] = (v4f)0.f;
            accIm[mi][ni] = (v4f)0.f;
        }

    for (int c = 0; c < 4; ++c) {
        __syncthreads();                             // LDS safe to overwrite
        const int cbyte = c * 128;                   // 64 elems * 2 B
#pragma unroll
        for (int p = 0; p < 4; ++p) {
            const int lo = p * 4096 + lbase;
            const char* sA = gA + cbyte + goff[p];
            const char* sK = gK + cbyte + goff[p];
            __builtin_amdgcn_global_load_lds(
                (const __attribute__((address_space(1))) void*)sA,
                (__attribute__((address_space(3))) void*)((char*)lAc + lo), 16, 0, 0);
            __builtin_amdgcn_global_load_lds(
                (const __attribute__((address_space(1))) void*)(sA + 512),
                (__attribute__((address_space(3))) void*)((char*)lAs + lo), 16, 0, 0);
            __builtin_amdgcn_global_load_lds(
                (const __attribute__((address_space(1))) void*)sK,
                (__attribute__((address_space(3))) void*)((char*)lKc + lo), 16, 0, 0);
            __builtin_amdgcn_global_load_lds(
                (const __attribute__((address_space(1))) void*)(sK + 512),
                (__attribute__((address_space(3))) void*)((char*)lKs + lo), 16, 0, 0);
        }
        __syncthreads();                             // drain staging

#pragma unroll
        for (int ks2 = 0; ks2 < 2; ++ks2) {
            const int sl = ((ks2 * 4 + qq) ^ (r15 & 7)) * 8;
            v8s aqf[4], asf[4];
#pragma unroll
            for (int mi = 0; mi < 4; ++mi) {
                const int off = (wm * 64 + mi * 16 + r15) * 64 + sl;
                aqf[mi] = *(const v8s*)&lAc[off];
                asf[mi] = *(const v8s*)&lAs[off];
            }
#pragma unroll
            for (int ni = 0; ni < 4; ++ni) {
                const int koff = (wn * 64 + ni * 16 + r15) * 64 + sl;
                const v8s kc = *(const v8s*)&lKc[koff];
                const v8s ks = *(const v8s*)&lKs[koff];
                v4i kci = __builtin_bit_cast(v4i, kc);
                kci ^= (int)0x80008000;              // bf16 sign flip: -ck
                const v8s nkc = __builtin_bit_cast(v8s, kci);
#pragma unroll
                for (int mi = 0; mi < 4; ++mi) {
                    accRe[mi][ni] = __builtin_amdgcn_mfma_f32_16x16x32_bf16(aqf[mi], kc,  accRe[mi][ni], 0, 0, 0);
                    accRe[mi][ni] = __builtin_amdgcn_mfma_f32_16x16x32_bf16(asf[mi], ks,  accRe[mi][ni], 0, 0, 0);
                    accIm[mi][ni] = __builtin_amdgcn_mfma_f32_16x16x32_bf16(aqf[mi], ks,  accIm[mi][ni], 0, 0, 0);
                    accIm[mi][ni] = __builtin_amdgcn_mfma_f32_16x16x32_bf16(asf[mi], nkc, accIm[mi][ni], 0, 0, 0);
                }
            }
        }
    }

    // ---- Epilogue: attn -> LDS bf16 [128][136]; V^T -> LDS bf16 [16][136] ----
    __syncthreads();                                 // all frag reads done

    const float sc = 3.0517578125e-05f;              // 2^-15
    // C-layout (m89): col = lane&15, row = (lane>>4)*4 + reg
#pragma unroll
    for (int mi = 0; mi < 4; ++mi) {
#pragma unroll
        for (int ni = 0; ni < 4; ++ni) {
#pragma unroll
            for (int rg = 0; rg < 4; ++rg) {
                const float re = accRe[mi][ni][rg];
                const float im = accIm[mi][ni][rg];
                const float a  = fmaf(re * re + im * im, sc, -1.0f);
                const int row = wm * 64 + mi * 16 + qq * 4 + rg;
                const int col = wn * 64 + ni * 16 + r15;
                __hip_bfloat16 ab = __float2bfloat16(a);
                lattn[row * 136 + col] = *(const uint16_t*)&ab;
            }
        }
    }
    {   // V^T: lVt[e][j] = bf16(V[b][jblk*128+j][e]);  e rows 8..15 hold
        // leftover staged bf16 (finite) -> output cols 8..15 garbage, unused.
        const int j = tid >> 1, eh = (tid & 1) * 4;
        const float vv[4] = {vreg.x, vreg.y, vreg.z, vreg.w};
#pragma unroll
        for (int c2 = 0; c2 < 4; ++c2) {
            __hip_bfloat16 vb = __float2bfloat16(vv[c2]);
            lVt[(eh + c2) * 136 + j] = *(const uint16_t*)&vb;
        }
    }
    __syncthreads();

    // ---- Phase 2: out-tile = attnTile[128x128] @ Vt^T via MFMA ----
    v8s bfr[4];
#pragma unroll
    for (int ks3 = 0; ks3 < 4; ++ks3)
        bfr[ks3] = *(const v8s*)&lVt[r15 * 136 + ks3 * 32 + qq * 8];

    float* outb = out + (((size_t)b << 10) + iblk * 128) * E_Q;
#pragma unroll
    for (int mt = 0; mt < 2; ++mt) {
        const int rowbase = (wv * 2 + mt) * 16;
        v4f accO = (v4f)0.f;
#pragma unroll
        for (int ks3 = 0; ks3 < 4; ++ks3) {
            const v8s af = *(const v8s*)&lattn[(rowbase + r15) * 136 + ks3 * 32 + qq * 8];
            accO = __builtin_amdgcn_mfma_f32_16x16x32_bf16(af, bfr[ks3], accO, 0, 0, 0);
        }
        if (r15 < E_Q) {
            const int i0 = rowbase + qq * 4;
#pragma unroll
            for (int rg = 0; rg < 4; ++rg)
                atomicAdd(&outb[(i0 + rg) * E_Q + r15], accO[rg]);
        }
    }
}

// ---------------------------------------------------------------------------
// Workspace layout (32 MB used):
//   [0,  16 MB)  Aq : Q tables, [16*1024][512] bf16
//   [16, 32 MB)  Kt : K tables, [16*1024][512] bf16
// d_out is zeroed by a memset node (it is 0xAA-poisoned before each replay)
// and accumulated via device-scope f32 atomicAdd (8 blocks per element).
// ---------------------------------------------------------------------------
extern "C" void kernel_launch(void* const* d_in, const int* in_sizes, int n_in,
                              void* d_out, int out_size, void* d_ws, size_t ws_size,
                              hipStream_t stream) {
    const float* Q = (const float*)d_in[0];
    const float* K = (const float*)d_in[1];
    const float* V = (const float*)d_in[2];
    float* out = (float*)d_out;

    uint16_t* Aq = (uint16_t*)d_ws;
    uint16_t* Kt = (uint16_t*)((char*)d_ws + (size_t)16 * 1024 * 1024);

    hipMemsetAsync(out, 0, (size_t)out_size * sizeof(float), stream);
    build_tables<<<dim3(NB * S_LEN / 16, 2), 256, 0, stream>>>(Q, K, Aq, Kt);
    qk_pv<<<dim3(S_LEN / 128, S_LEN / 128, NB), 256, 0, stream>>>(Aq, Kt, V, out);
}

// Round 4
// 89.763 us; speedup vs baseline: 1.7030x; 1.1407x over previous
//
#include <hip/hip_runtime.h>
#include <hip/hip_bf16.h>
#include <stdint.h>

// Problem constants (B=16, S=1024, E=8 qubits -> 2^8 = 256 amplitudes).
#define NB 16
#define S_LEN 1024
#define E_Q 8

typedef float v4f __attribute__((ext_vector_type(4)));
typedef short v8s __attribute__((ext_vector_type(8)));
typedef int   v4i __attribute__((ext_vector_type(4)));

// ---------------------------------------------------------------------------
// Kernel 1: per-token cos/sin feature tables, INT8 (scale 127).
//   L = sum_i x_i s_i,  phi = -0.5 L - 0.25 (L^2 - ||x||^2),  s_i=(-1)^{z_i}
// Q-table row (512 B): [round(127 cos phi(z)) | round(127 sin phi(z))]
// K-table row (768 B): [127 cos | 127 sin | -127 cos]  (third window feeds
//   the Im chain: Im = cq.sk + sq.(-ck); packed-i8 negate has no cheap VALU
//   form, so we pay 4 MB of table instead).
// Gray-code walk of the low nibble: one fma per z. i8 quantization error
// (+-0.0039 abs) adds ~2e-3 to out — negligible vs the 1.32 threshold.
// ---------------------------------------------------------------------------
__global__ __launch_bounds__(256) void build_tables(
    const float* __restrict__ Q, const float* __restrict__ K,
    int8_t* __restrict__ Aq, int8_t* __restrict__ Kt)
{
    const int which = blockIdx.y;
    const float* X = which ? K : Q;

    const int tok = blockIdx.x * 16 + (threadIdx.x >> 4);
    const int hi  = threadIdx.x & 15;     // z bits 4..7
    const int zb  = hi * 16;

    const float* x = X + tok * E_Q;
    float xv[E_Q]; float sq = 0.f;
#pragma unroll
    for (int i = 0; i < E_Q; ++i) { xv[i] = x[i]; sq += xv[i] * xv[i]; }
    const float qsq = 0.25f * sq;

    // L at z = zb: low 4 bits 0 (sign +), high bits from `hi`.
    float L = xv[0] + xv[1] + xv[2] + xv[3];
#pragma unroll
    for (int i = 4; i < 8; ++i) L += ((hi >> (i - 4)) & 1) ? -xv[i] : xv[i];

    __align__(16) int8_t cb[16];
    __align__(16) int8_t sb[16];

    {   // n = 0, gray = 0
        const float phi = fmaf(-0.25f, L * L, fmaf(-0.5f, L, qsq));
        float s, c; __sincosf(phi, &s, &c);
        cb[0] = (int8_t)__float2int_rn(127.f * c);
        sb[0] = (int8_t)__float2int_rn(127.f * s);
    }
#pragma unroll
    for (int n = 1; n < 16; ++n) {
        const int g  = n ^ (n >> 1);
        const int gp = (n - 1) ^ ((n - 1) >> 1);
        const int t  = __builtin_ctz(g ^ gp);        // constant-folds
        const float twox = 2.0f * xv[t];
        L = ((g >> t) & 1) ? (L - twox) : (L + twox);
        const float phi = fmaf(-0.25f, L * L, fmaf(-0.5f, L, qsq));
        float s, c; __sincosf(phi, &s, &c);
        cb[g] = (int8_t)__float2int_rn(127.f * c);
        sb[g] = (int8_t)__float2int_rn(127.f * s);
    }

    if (which == 0) {
        int8_t* dst = Aq + (size_t)tok * 512;
        *(uint4*)(dst + zb)       = *(const uint4*)cb;
        *(uint4*)(dst + 256 + zb) = *(const uint4*)sb;
    } else {
        __align__(16) int8_t nb[16];
#pragma unroll
        for (int i = 0; i < 16; ++i) nb[i] = (int8_t)(-cb[i]);
        int8_t* dst = Kt + (size_t)tok * 768;
        *(uint4*)(dst + zb)       = *(const uint4*)cb;
        *(uint4*)(dst + 256 + zb) = *(const uint4*)sb;
        *(uint4*)(dst + 512 + zb) = *(const uint4*)nb;
    }
}

// ---------------------------------------------------------------------------
// Kernel 2: fused QK fidelity GEMM (i8) + nonlinearity + MFMA PV + atomics.
// Per c-iter (c=0..3) stage three [128][128B] i8 tiles (48 KB total):
//   lA  <- A-chunk c  of [cq|sq]        (row stride 512)
//   lK0 <- K-chunk c  of [ck|sk|-ck]    (row stride 768)  -> Re chain
//   lK1 <- K-chunk c+2                  -> Im chain (cq.sk + sq.(-ck))
// XOR chunk swizzle (slot = q ^ (row&7)) -> uniform bank spread on v4i
// frag reads. 2 K-windows of 64 per chunk -> 64 mfma_i32_16x16x64_i8 per
// wave per iter (half the bf16 instr count at 2x the MAC rate).
// accRe/accIm are exact i32 (|.| <= 512*127^2 < 2^23).
// attn = (Re^2+Im^2) * 2^-15/127^4 - 1 -> bf16 LDS [128][136]; PV via
// bf16 MFMA (V^T [16][136]); f32 atomicAdd into memset-zeroed d_out.
// ---------------------------------------------------------------------------
__global__ __launch_bounds__(256, 2) void qk_pv(
    const int8_t* __restrict__ Aq, const int8_t* __restrict__ Kt,
    const float* __restrict__ V, float* __restrict__ out)
{
    __shared__ __align__(16) char smem[49152];
    int8_t* lA  = (int8_t*)smem;                    // [128][128] i8
    int8_t* lK0 = (int8_t*)(smem + 16384);
    int8_t* lK1 = (int8_t*)(smem + 32768);
    // phase-2 aliases (valid after the post-K-loop barrier)
    uint16_t* lattn = (uint16_t*)smem;              // [128][136] bf16
    uint16_t* lVt   = (uint16_t*)(smem + 34816);    // [16][136]  bf16 (V^T)

    const int jblk = blockIdx.x, iblk = blockIdx.y, b = blockIdx.z;
    const int tid  = threadIdx.x;
    const int lane = tid & 63, wv = tid >> 6;
    const int wm = wv >> 1, wn = wv & 1;            // wave quadrant
    const int r15 = lane & 15, qq = lane >> 4;

    // Staging: tile = 1024 16B-chunks; thread stages chunk f = p*256+tid.
    // LDS byte f*16 (wave-uniform base + lane*16); source row r = f>>3,
    // swizzled logical chunk q = (f&7) ^ (r&7).
    int goffA[4], goffK[4];
#pragma unroll
    for (int p = 0; p < 4; ++p) {
        const int f = p * 256 + tid;
        const int r = f >> 3, q = (f & 7) ^ (r & 7);
        goffA[p] = r * 512 + q * 16;
        goffK[p] = r * 768 + q * 16;
    }
    const int lbase = wv * 1024;                     // wave-uniform LDS base

    const int8_t* gA = Aq + (size_t)(b * S_LEN + iblk * 128) * 512;
    const int8_t* gK = Kt + (size_t)(b * S_LEN + jblk * 128) * 768;

    // V tile load issued early: V[b][jblk*128 + (tid>>1)][(tid&1)*4 .. +4]
    const float4 vreg = ((const float4*)(V + ((size_t)b * S_LEN + jblk * 128) * E_Q))[tid];

    v4i accRe[4][4], accIm[4][4];
#pragma unroll
    for (int mi = 0; mi < 4; ++mi)
#pragma unroll
        for (int ni = 0; ni < 4; ++ni) {
            accRe[mi][ni] = (v4i)0;
            accIm[mi][ni] = (v4i)0;
        }

    for (int c = 0; c < 4; ++c) {
        __syncthreads();                             // LDS safe to overwrite
        const int cbyte = c * 128;
#pragma unroll
        for (int p = 0; p < 4; ++p) {
            const int lo = p * 4096 + lbase;
            __builtin_amdgcn_global_load_lds(
                (const __attribute__((address_space(1))) void*)(gA + cbyte + goffA[p]),
                (__attribute__((address_space(3))) void*)(lA + lo), 16, 0, 0);
            __builtin_amdgcn_global_load_lds(
                (const __attribute__((address_space(1))) void*)(gK + cbyte + goffK[p]),
                (__attribute__((address_space(3))) void*)(lK0 + lo), 16, 0, 0);
            __builtin_amdgcn_global_load_lds(
                (const __attribute__((address_space(1))) void*)(gK + 256 + cbyte + goffK[p]),
                (__attribute__((address_space(3))) void*)(lK1 + lo), 16, 0, 0);
        }
        __syncthreads();                             // drain staging

#pragma unroll
        for (int w = 0; w < 2; ++w) {
            v4i aF[4];
#pragma unroll
            for (int mi = 0; mi < 4; ++mi) {
                const int row = wm * 64 + mi * 16 + r15;
                aF[mi] = *(const v4i*)&lA[row * 128 + (((w << 2) | qq) ^ (row & 7)) * 16];
            }
#pragma unroll
            for (int ni = 0; ni < 4; ++ni) {
                const int rk  = wn * 64 + ni * 16 + r15;
                const int off = rk * 128 + (((w << 2) | qq) ^ (rk & 7)) * 16;
                const v4i k0 = *(const v4i*)&lK0[off];
                const v4i k1 = *(const v4i*)&lK1[off];
#pragma unroll
                for (int mi = 0; mi < 4; ++mi) {
                    accRe[mi][ni] = __builtin_amdgcn_mfma_i32_16x16x64_i8(aF[mi], k0, accRe[mi][ni], 0, 0, 0);
                    accIm[mi][ni] = __builtin_amdgcn_mfma_i32_16x16x64_i8(aF[mi], k1, accIm[mi][ni], 0, 0, 0);
                }
            }
        }
    }

    // ---- Epilogue: attn -> LDS bf16 [128][136]; V^T -> LDS bf16 [16][136] ----
    __syncthreads();                                 // all frag reads done

    const float sc2 = 3.0517578125e-05f / 260144641.0f;   // 2^-15 / 127^4
    // C-layout (m89): col = lane&15, row = (lane>>4)*4 + reg
#pragma unroll
    for (int mi = 0; mi < 4; ++mi) {
#pragma unroll
        for (int ni = 0; ni < 4; ++ni) {
#pragma unroll
            for (int rg = 0; rg < 4; ++rg) {
                const float rf  = (float)accRe[mi][ni][rg];
                const float imf = (float)accIm[mi][ni][rg];
                const float a   = fmaf(rf * rf + imf * imf, sc2, -1.0f);
                const int row = wm * 64 + mi * 16 + qq * 4 + rg;
                const int col = wn * 64 + ni * 16 + r15;
                __hip_bfloat16 ab = __float2bfloat16(a);
                lattn[row * 136 + col] = *(const uint16_t*)&ab;
            }
        }
    }
    {   // V^T: lVt[e][j] = bf16(V[b][jblk*128+j][e]); rows 8..15 hold stale
        // staged i8 bytes (finite as bf16) -> output cols 8..15 garbage, unused.
        const int j = tid >> 1, eh = (tid & 1) * 4;
        const float vv[4] = {vreg.x, vreg.y, vreg.z, vreg.w};
#pragma unroll
        for (int c2 = 0; c2 < 4; ++c2) {
            __hip_bfloat16 vb = __float2bfloat16(vv[c2]);
            lVt[(eh + c2) * 136 + j] = *(const uint16_t*)&vb;
        }
    }
    __syncthreads();

    // ---- Phase 2: out-tile = attnTile[128x128] @ Vt^T via bf16 MFMA ----
    v8s bfr[4];
#pragma unroll
    for (int ks3 = 0; ks3 < 4; ++ks3)
        bfr[ks3] = *(const v8s*)&lVt[r15 * 136 + ks3 * 32 + qq * 8];

    float* outb = out + (((size_t)b << 10) + iblk * 128) * E_Q;
#pragma unroll
    for (int mt = 0; mt < 2; ++mt) {
        const int rowbase = (wv * 2 + mt) * 16;
        v4f accO = (v4f)0.f;
#pragma unroll
        for (int ks3 = 0; ks3 < 4; ++ks3) {
            const v8s af = *(const v8s*)&lattn[(rowbase + r15) * 136 + ks3 * 32 + qq * 8];
            accO = __builtin_amdgcn_mfma_f32_16x16x32_bf16(af, bfr[ks3], accO, 0, 0, 0);
        }
        if (r15 < E_Q) {
            const int i0 = rowbase + qq * 4;
#pragma unroll
            for (int rg = 0; rg < 4; ++rg)
                atomicAdd(&outb[(i0 + rg) * E_Q + r15], accO[rg]);
        }
    }
}

// ---------------------------------------------------------------------------
// Workspace layout (20 MB used):
//   [0,   8 MB)  Aq : Q tables, [16*1024][512] i8
//   [8,  20 MB)  Kt : K tables, [16*1024][768] i8  ([ck|sk|-ck])
// d_out is zeroed by a memset node (0xAA-poisoned before each replay) and
// accumulated via device-scope f32 atomicAdd (8 blocks per element).
// ---------------------------------------------------------------------------
extern "C" void kernel_launch(void* const* d_in, const int* in_sizes, int n_in,
                              void* d_out, int out_size, void* d_ws, size_t ws_size,
                              hipStream_t stream) {
    const float* Q = (const float*)d_in[0];
    const float* K = (const float*)d_in[1];
    const float* V = (const float*)d_in[2];
    float* out = (float*)d_out;

    int8_t* Aq = (int8_t*)d_ws;
    int8_t* Kt = (int8_t*)((char*)d_ws + (size_t)8 * 1024 * 1024);

    hipMemsetAsync(out, 0, (size_t)out_size * sizeof(float), stream);
    build_tables<<<dim3(NB * S_LEN / 16, 2), 256, 0, stream>>>(Q, K, Aq, Kt);
    qk_pv<<<dim3(S_LEN / 128, S_LEN / 128, NB), 256, 0, stream>>>(Aq, Kt, V, out);
}

// Round 6
// 88.516 us; speedup vs baseline: 1.7270x; 1.0141x over previous
//
#include <hip/hip_runtime.h>
#include <hip/hip_bf16.h>
#include <stdint.h>

// Problem constants (B=16, S=1024, E=8 qubits -> 2^8 = 256 amplitudes).
#define NB 16
#define S_LEN 1024
#define E_Q 8

typedef float v4f __attribute__((ext_vector_type(4)));
typedef short v8s __attribute__((ext_vector_type(8)));
typedef int   v4i __attribute__((ext_vector_type(4)));

// ---------------------------------------------------------------------------
// Kernel 1: per-token cos/sin feature tables, INT8 (scale 127).
//   L = sum_i x_i s_i,  phi = -0.5 L - 0.25 (L^2 - ||x||^2),  s_i=(-1)^{z_i}
// Q-table row (512 B): [round(127 cos phi) | round(127 sin phi)]
// K-table row (768 B): [127 cos | 127 sin | -127 cos]  (third window feeds
//   the Im chain: Im = cq.sk + sq.(-ck)).
// Gray-code walk of the low nibble: one fma per z.
// Side job: the first 128 blocks of the which==0 half zero d_out
// (32768 float4 == 131072 floats exactly; R5 bug was writing 8 MB OOB here).
// ---------------------------------------------------------------------------
__global__ __launch_bounds__(256) void build_tables(
    const float* __restrict__ Q, const float* __restrict__ K,
    int8_t* __restrict__ Aq, int8_t* __restrict__ Kt,
    float* __restrict__ out)
{
    const int which = blockIdx.y;
    const float* X = which ? K : Q;

    if (which == 0 && blockIdx.x < 128) {   // zero d_out: 128*256 float4
        float4 z; z.x = z.y = z.z = z.w = 0.f;
        ((float4*)out)[blockIdx.x * 256 + threadIdx.x] = z;
    }

    const int tok = blockIdx.x * 16 + (threadIdx.x >> 4);
    const int hi  = threadIdx.x & 15;     // z bits 4..7
    const int zb  = hi * 16;

    const float* x = X + tok * E_Q;
    float xv[E_Q]; float sq = 0.f;
#pragma unroll
    for (int i = 0; i < E_Q; ++i) { xv[i] = x[i]; sq += xv[i] * xv[i]; }
    const float qsq = 0.25f * sq;

    // L at z = zb: low 4 bits 0 (sign +), high bits from `hi`.
    float L = xv[0] + xv[1] + xv[2] + xv[3];
#pragma unroll
    for (int i = 4; i < 8; ++i) L += ((hi >> (i - 4)) & 1) ? -xv[i] : xv[i];

    __align__(16) int8_t cb[16];
    __align__(16) int8_t sb[16];

    {   // n = 0, gray = 0
        const float phi = fmaf(-0.25f, L * L, fmaf(-0.5f, L, qsq));
        float s, c; __sincosf(phi, &s, &c);
        cb[0] = (int8_t)__float2int_rn(127.f * c);
        sb[0] = (int8_t)__float2int_rn(127.f * s);
    }
#pragma unroll
    for (int n = 1; n < 16; ++n) {
        const int g  = n ^ (n >> 1);
        const int gp = (n - 1) ^ ((n - 1) >> 1);
        const int t  = __builtin_ctz(g ^ gp);        // constant-folds
        const float twox = 2.0f * xv[t];
        L = ((g >> t) & 1) ? (L - twox) : (L + twox);
        const float phi = fmaf(-0.25f, L * L, fmaf(-0.5f, L, qsq));
        float s, c; __sincosf(phi, &s, &c);
        cb[g] = (int8_t)__float2int_rn(127.f * c);
        sb[g] = (int8_t)__float2int_rn(127.f * s);
    }

    if (which == 0) {
        int8_t* dst = Aq + (size_t)tok * 512;
        *(uint4*)(dst + zb)       = *(const uint4*)cb;
        *(uint4*)(dst + 256 + zb) = *(const uint4*)sb;
    } else {
        __align__(16) int8_t nb[16];
#pragma unroll
        for (int i = 0; i < 16; ++i) nb[i] = (int8_t)(-cb[i]);
        int8_t* dst = Kt + (size_t)tok * 768;
        *(uint4*)(dst + zb)       = *(const uint4*)cb;
        *(uint4*)(dst + 256 + zb) = *(const uint4*)sb;
        *(uint4*)(dst + 512 + zb) = *(const uint4*)nb;
    }
}

// ---------------------------------------------------------------------------
// Kernel 2: fused QK fidelity GEMM (i8) + nonlinearity + MFMA PV + atomics.
// Phase 1: per c-iter (c=0..3) stage three [128][128B] i8 tiles (48 KB):
//   lA  <- Q-chunk c of [cq|sq]      (row stride 512)
//   lK0 <- K-chunk c of [ck|sk|-ck]  (row stride 768)  -> Re chain
//   lK1 <- K-chunk c+2               -> Im chain (cq.sk + sq.(-ck))
// MFMA with A=K-frag, B=Q-frag => D rows=j, cols=i (C^T trick): each thread
// then holds 4 CONSECUTIVE j at fixed i, so the attn epilogue is 16 packed
// b64 LDS writes instead of 64 scattered u16 (the R2 3.7M-conflict hot spot),
// while lattn stays [i][136+j] row-major — phase-2 PV unchanged.
// accRe/accIm exact i32. attn = (Re^2+Im^2)*2^-15/127^4 - 1 -> bf16 LDS;
// PV via bf16 MFMA (V^T [16][136]); f32 atomicAdd into pre-zeroed d_out.
// ---------------------------------------------------------------------------
__global__ __launch_bounds__(256, 2) void qk_pv(
    const int8_t* __restrict__ Aq, const int8_t* __restrict__ Kt,
    const float* __restrict__ V, float* __restrict__ out)
{
    __shared__ __align__(16) char smem[49152];
    int8_t* lA  = (int8_t*)smem;                    // [128][128] i8 (Q side)
    int8_t* lK0 = (int8_t*)(smem + 16384);
    int8_t* lK1 = (int8_t*)(smem + 32768);
    // phase-2 aliases (valid after the post-K-loop barrier)
    uint16_t* lattn = (uint16_t*)smem;              // [128][136] bf16, rows=i
    uint16_t* lVt   = (uint16_t*)(smem + 34816);    // [16][136]  bf16 (V^T)

    const int jblk = blockIdx.x, iblk = blockIdx.y, b = blockIdx.z;
    const int tid  = threadIdx.x;
    const int lane = tid & 63, wv = tid >> 6;
    const int wKj = wv >> 1, wQi = wv & 1;          // wave quadrant (j, i)
    const int r15 = lane & 15, qq = lane >> 4;

    // Staging: tile = 1024 16B-chunks; thread stages chunk f = p*256+tid.
    // LDS byte f*16 (wave-uniform base + lane*16); source row r = f>>3,
    // swizzled logical chunk q = (f&7) ^ (r&7).
    int goffA[4], goffK[4];
#pragma unroll
    for (int p = 0; p < 4; ++p) {
        const int f = p * 256 + tid;
        const int r = f >> 3, q = (f & 7) ^ (r & 7);
        goffA[p] = r * 512 + q * 16;
        goffK[p] = r * 768 + q * 16;
    }
    const int lbase = wv * 1024;                     // wave-uniform LDS base

    const int8_t* gA = Aq + (size_t)(b * S_LEN + iblk * 128) * 512;
    const int8_t* gK = Kt + (size_t)(b * S_LEN + jblk * 128) * 768;

    // V tile load issued early: V[b][jblk*128 + (tid>>1)][(tid&1)*4 .. +4]
    const float4 vreg = ((const float4*)(V + ((size_t)b * S_LEN + jblk * 128) * E_Q))[tid];

    v4i accRe[4][4], accIm[4][4];                    // [nj][mi]
#pragma unroll
    for (int nj = 0; nj < 4; ++nj)
#pragma unroll
        for (int mi = 0; mi < 4; ++mi) {
            accRe[nj][mi] = (v4i)0;
            accIm[nj][mi] = (v4i)0;
        }

    for (int c = 0; c < 4; ++c) {
        __syncthreads();                             // LDS safe to overwrite
        const int cbyte = c * 128;
#pragma unroll
        for (int p = 0; p < 4; ++p) {
            const int lo = p * 4096 + lbase;
            __builtin_amdgcn_global_load_lds(
                (const __attribute__((address_space(1))) void*)(gA + cbyte + goffA[p]),
                (__attribute__((address_space(3))) void*)(lA + lo), 16, 0, 0);
            __builtin_amdgcn_global_load_lds(
                (const __attribute__((address_space(1))) void*)(gK + cbyte + goffK[p]),
                (__attribute__((address_space(3))) void*)(lK0 + lo), 16, 0, 0);
            __builtin_amdgcn_global_load_lds(
                (const __attribute__((address_space(1))) void*)(gK + 256 + cbyte + goffK[p]),
                (__attribute__((address_space(3))) void*)(lK1 + lo), 16, 0, 0);
        }
        __syncthreads();                             // drain staging

#pragma unroll
        for (int w = 0; w < 2; ++w) {
            v4i qF[4];                               // B-operand (Q side)
#pragma unroll
            for (int mi = 0; mi < 4; ++mi) {
                const int row = wQi * 64 + mi * 16 + r15;
                qF[mi] = *(const v4i*)&lA[row * 128 + (((w << 2) | qq) ^ (row & 7)) * 16];
            }
#pragma unroll
            for (int nj = 0; nj < 4; ++nj) {
                const int rk  = wKj * 64 + nj * 16 + r15;
                const int off = rk * 128 + (((w << 2) | qq) ^ (rk & 7)) * 16;
                const v4i k0 = *(const v4i*)&lK0[off];   // A-operand (K side)
                const v4i k1 = *(const v4i*)&lK1[off];
#pragma unroll
                for (int mi = 0; mi < 4; ++mi) {
                    accRe[nj][mi] = __builtin_amdgcn_mfma_i32_16x16x64_i8(k0, qF[mi], accRe[nj][mi], 0, 0, 0);
                    accIm[nj][mi] = __builtin_amdgcn_mfma_i32_16x16x64_i8(k1, qF[mi], accIm[nj][mi], 0, 0, 0);
                }
            }
        }
    }

    // ---- Epilogue: attn -> LDS bf16 [i][136+j]; V^T -> LDS bf16 [16][136] ----
    __syncthreads();                                 // all frag reads done

    const float sc2 = 3.0517578125e-05f / 260144641.0f;   // 2^-15 / 127^4
    // C^T layout: D row = j = wKj*64 + nj*16 + qq*4 + rg,  col = i = wQi*64
    // + mi*16 + r15.  4 consecutive j at fixed i -> one packed b64 store.
#pragma unroll
    for (int nj = 0; nj < 4; ++nj) {
#pragma unroll
        for (int mi = 0; mi < 4; ++mi) {
            uint64_t pk = 0;
#pragma unroll
            for (int rg = 0; rg < 4; ++rg) {
                const float rf  = (float)accRe[nj][mi][rg];
                const float imf = (float)accIm[nj][mi][rg];
                const float a   = fmaf(rf * rf + imf * imf, sc2, -1.0f);
                __hip_bfloat16 ab = __float2bfloat16(a);
                pk |= (uint64_t)(*(const uint16_t*)&ab) << (16 * rg);
            }
            const int i  = wQi * 64 + mi * 16 + r15;
            const int j0 = wKj * 64 + nj * 16 + qq * 4;
            *(uint64_t*)&lattn[i * 136 + j0] = pk;
        }
    }
    {   // V^T: lVt[e][j] = bf16(V[b][jblk*128+j][e]); rows 8..15 hold stale
        // staged i8 bytes (finite as bf16) -> output cols 8..15 garbage, unused.
        const int j = tid >> 1, eh = (tid & 1) * 4;
        const float vv[4] = {vreg.x, vreg.y, vreg.z, vreg.w};
#pragma unroll
        for (int c2 = 0; c2 < 4; ++c2) {
            __hip_bfloat16 vb = __float2bfloat16(vv[c2]);
            lVt[(eh + c2) * 136 + j] = *(const uint16_t*)&vb;
        }
    }
    __syncthreads();

    // ---- Phase 2: out-tile = attnTile[128x128] @ Vt^T via bf16 MFMA ----
    v8s bfr[4];
#pragma unroll
    for (int ks3 = 0; ks3 < 4; ++ks3)
        bfr[ks3] = *(const v8s*)&lVt[r15 * 136 + ks3 * 32 + qq * 8];

    float* outb = out + (((size_t)b << 10) + iblk * 128) * E_Q;
#pragma unroll
    for (int mt = 0; mt < 2; ++mt) {
        const int rowbase = (wv * 2 + mt) * 16;
        v4f accO = (v4f)0.f;
#pragma unroll
        for (int ks3 = 0; ks3 < 4; ++ks3) {
            const v8s af = *(const v8s*)&lattn[(rowbase + r15) * 136 + ks3 * 32 + qq * 8];
            accO = __builtin_amdgcn_mfma_f32_16x16x32_bf16(af, bfr[ks3], accO, 0, 0, 0);
        }
        if (r15 < E_Q) {
            const int i0 = rowbase + qq * 4;
#pragma unroll
            for (int rg = 0; rg < 4; ++rg)
                atomicAdd(&outb[(i0 + rg) * E_Q + r15], accO[rg]);
        }
    }
}

// ---------------------------------------------------------------------------
// Workspace layout (20 MB used):
//   [0,   8 MB)  Aq : Q tables, [16*1024][512] i8
//   [8,  20 MB)  Kt : K tables, [16*1024][768] i8  ([ck|sk|-ck])
// d_out is zeroed inside build_tables (0xAA-poisoned before each replay) and
// accumulated via device-scope f32 atomicAdd (8 blocks per element).
// ---------------------------------------------------------------------------
extern "C" void kernel_launch(void* const* d_in, const int* in_sizes, int n_in,
                              void* d_out, int out_size, void* d_ws, size_t ws_size,
                              hipStream_t stream) {
    const float* Q = (const float*)d_in[0];
    const float* K = (const float*)d_in[1];
    const float* V = (const float*)d_in[2];
    float* out = (float*)d_out;

    int8_t* Aq = (int8_t*)d_ws;
    int8_t* Kt = (int8_t*)((char*)d_ws + (size_t)8 * 1024 * 1024);

    build_tables<<<dim3(NB * S_LEN / 16, 2), 256, 0, stream>>>(Q, K, Aq, Kt, out);
    qk_pv<<<dim3(S_LEN / 128, S_LEN / 128, NB), 256, 0, stream>>>(Aq, Kt, V, out);
}